// Round 5
// baseline (141.861 us; speedup 1.0000x reference)
//
#include <hip/hip_runtime.h>
#include <hip/hip_bf16.h>
#include <math.h>

// out[b,i,p] = sqrt(yr^2+yi^2); yr/yi = (Hr/Hi[b] @ x[b])*scale + noise*0.01
// B=32, C=256, P=3136. Memory-bound (~292MB observed HBM -> ~46us floor).
// Round-5: fixes round-4's race. vmcnt is PER-WAVE, so the counted wait must
// come BEFORE s_barrier (own DMA retired -> barrier -> all waves' DMA retired).
// Depth-2 pipeline, one barrier/iter, counted vmcnt(4) steady state.

#define NBATCH 32
#define NC 256
#define NP 3136
#define BM 128
#define BN 64
#define BK 32
#define NBN 49
#define NKI 8          // 256/32 K-steps

typedef __attribute__((ext_vector_type(8))) short short8;
typedef __attribute__((ext_vector_type(4))) float f32x4;

static __device__ __forceinline__ void gload16(const void* g, void* l) {
  __builtin_amdgcn_global_load_lds(
      (const __attribute__((address_space(1))) void*)g,
      (__attribute__((address_space(3))) void*)l, 16, 0, 0);
}

static __device__ __forceinline__ unsigned short bfr(float f) {
  __hip_bfloat16 h = __float2bfloat16(f);   // RNE; pairs into v_cvt_pk_bf16_f32
  return *reinterpret_cast<unsigned short*>(&h);
}

// ---- pre-pass: Hr/Hi fp32 -> bf16 in workspace (2 x 2,097,152 elems) ----
__global__ __launch_bounds__(256)
void cvt_h_kernel(const float* __restrict__ hr, const float* __restrict__ hi,
                  unsigned short* __restrict__ hrb, unsigned short* __restrict__ hib)
{
  const size_t i4 = ((size_t)blockIdx.x * 256 + threadIdx.x) * 4;
  const float4 r = *reinterpret_cast<const float4*>(hr + i4);
  const float4 s = *reinterpret_cast<const float4*>(hi + i4);
  union { uint2 v; unsigned short u[4]; } o1, o2;
  o1.u[0] = bfr(r.x); o1.u[1] = bfr(r.y); o1.u[2] = bfr(r.z); o1.u[3] = bfr(r.w);
  o2.u[0] = bfr(s.x); o2.u[1] = bfr(s.y); o2.u[2] = bfr(s.z); o2.u[3] = bfr(s.w);
  *reinterpret_cast<uint2*>(hrb + i4) = o1.v;
  *reinterpret_cast<uint2*>(hib + i4) = o2.v;
}

// x LDS: fp32 [k 0..31][p 0..63], phys 16B-chunk = logical ^ swz(k>>3) (0 bank
// conflicts, verified r2/r3). H LDS: bf16 [fq][row][8] (2-way = free).
// Pipeline (PRE=1): per-wave vmem FIFO per iter = stage(t+1)[3] then noise(t)[4].
// At wait of iter t (BEFORE barrier), own queue oldest-first:
//   stage(t)[3] | noise(t-1)[4]   -> vmcnt(4) retires stage(t); t==0: vmcnt(0).
// vmcnt retires in issue order, so <=4 outstanding == only noise(t-1) left.
// Buffer safety: reads of buf[t&1] are consumed by MFMAs (lgkmcnt) before a
// wave reaches barrier(t+1), so stage(t+2)'s DMA overwrite post-barrier is safe.
template<int PRE>
__global__ __launch_bounds__(512, 4)
void rayleigh_main(const float* __restrict__ xg,
                   const float* __restrict__ Hrg,
                   const float* __restrict__ Hig,
                   const unsigned short* __restrict__ Hrb,
                   const unsigned short* __restrict__ Hib,
                   const float* __restrict__ nrg,
                   const float* __restrict__ nig,
                   float* __restrict__ outg)
{
  __shared__ float x_lds[2][BK * BN];            // 2 x 8KB
  __shared__ unsigned short hr_lds[2][4096];     // 2 x 8KB  [fq][row][8]
  __shared__ unsigned short hi_lds[2][4096];     // 2 x 8KB

  // XCD-chunked bijection: 3136 = 8*392 = 8 * (4 batches * 98). Each XCD owns
  // 4 whole batches -> x[b] (3.2MB) + H slab L2-resident per XCD.
  const int raw = blockIdx.x;
  const int v   = (raw & 7) * 392 + (raw >> 3);
  const int b   = v / 98;
  const int r2  = v - b * 98;
  const int bm  = r2 / 49;
  const int bn  = r2 - bm * 49;

  const int tid  = threadIdx.x;
  const int lane = tid & 63;
  const int wave = tid >> 6;      // 8 waves: 2(M) x 4(N)
  const int wm   = wave >> 2;
  const int wn   = wave & 3;
  const int fr   = lane & 15;
  const int fq   = lane >> 4;

  const float* xsrc = xg + (size_t)b * NC * NP + (size_t)bn * BN;
  const size_t hrowbase = (size_t)b * NC + bm * BM;

  // stage one K-tile: x 8KB (8 chunks, wave w -> chunk w) + hr/hi 8KB each
  // (16 chunks, wave w -> chunks 2w, 2w+1). All async DMA; 3 vmem ops/wave.
  auto stage = [&](int t, int buf) {
    {
      const int C16 = wave * 64 + lane;          // 16B chunk idx in 8KB x-tile
      const int k   = C16 >> 4;
      const int cp  = C16 & 15;
      const int fqk = k >> 3;
      const int cl  = cp ^ (((fqk & 1) << 2) | (fqk >> 1));
      const float* src = xsrc + (size_t)(t * BK + k) * NP + cl * 4;
      gload16(src, (char*)x_lds[buf] + wave * 1024);
    }
    if constexpr (PRE) {
      #pragma unroll
      for (int i = 0; i < 2; ++i) {
        const int c    = wave * 2 + i;           // 0..15
        const unsigned short* hb = (c & 8) ? Hib : Hrb;
        unsigned short* hl = (c & 8) ? hi_lds[buf] : hr_lds[buf];
        const int fqc  = (c >> 1) & 3;
        const int half = c & 1;
        const unsigned short* src =
            hb + (hrowbase + half * 64 + lane) * NC + t * BK + fqc * 8;
        gload16(src, (char*)hl + fqc * 2048 + half * 1024);
      }
    }
  };

  f32x4 accR[4], accI[4];
  #pragma unroll
  for (int m = 0; m < 4; ++m) {
    accR[m] = (f32x4){0.f, 0.f, 0.f, 0.f};
    accI[m] = (f32x4){0.f, 0.f, 0.f, 0.f};
  }
  float nrv[4][4], niv[4][4];

  const size_t obase = ((size_t)b * NC + bm * BM + wm * 64 + fq * 4) * NP
                     + (size_t)bn * BN + wn * 16 + fr;
  const int xork = ((fq & 1) << 6) | ((fq >> 1) << 4);
  const int pcol = ((wn * 16 + fr) << 2) ^ xork;

  stage(0, 0);

  #pragma unroll
  for (int t = 0; t < NKI; ++t) {
    if constexpr (PRE) {
      // own stage(t) retired FIRST, then barrier => ALL waves' stage(t) landed
      if (t == 0) asm volatile("s_waitcnt vmcnt(0)" ::: "memory");
      else        asm volatile("s_waitcnt vmcnt(4)" ::: "memory");
      __builtin_amdgcn_s_barrier();
      __builtin_amdgcn_sched_barrier(0);   // rule #18: no LDS-read hoisting
    } else {
      __syncthreads();
    }
    if (t + 1 < NKI) stage(t + 1, (t + 1) & 1);

    // noise prefetch chunk t: 4 plain dword loads (L2/L3-cacheable), 1 iter
    // of latency hiding before the next iter's vmcnt(4) can force retirement
    {
      const int m = t >> 1, rb = (t & 1) * 2;
      #pragma unroll
      for (int r = 0; r < 2; ++r) {
        const size_t idx = obase + (size_t)(m * 16 + rb + r) * NP;
        nrv[m][rb + r] = nrg[idx];
        niv[m][rb + r] = nig[idx];
      }
    }

    // B-fragment: 8 swizzled ds_read_b32 + pk-convert (0 bank conflicts)
    const char* xbuf = (const char*)x_lds[t & 1];
    union { short8 s; unsigned short u[8]; } u;
    #pragma unroll
    for (int j = 0; j < 8; ++j) {
      const float f = *reinterpret_cast<const float*>(xbuf + ((fq * 8 + j) << 8) + pcol);
      u.u[j] = bfr(f);
    }
    const short8 xb = u.s;

    // A-fragments from LDS (ds_read_b128, 2-way = free) + MFMA
    #pragma unroll
    for (int m = 0; m < 4; ++m) {
      const int row = wm * 64 + m * 16 + fr;
      short8 ar, ai;
      if constexpr (PRE) {
        ar = *reinterpret_cast<const short8*>(&hr_lds[t & 1][fq * 1024 + row * 8]);
        ai = *reinterpret_cast<const short8*>(&hi_lds[t & 1][fq * 1024 + row * 8]);
      } else {
        const float* p1 = Hrg + (hrowbase + row) * NC + t * BK + fq * 8;
        const float* p2 = Hig + (hrowbase + row) * NC + t * BK + fq * 8;
        const float4 v0 = *reinterpret_cast<const float4*>(p1);
        const float4 v1 = *reinterpret_cast<const float4*>(p1 + 4);
        const float4 w0 = *reinterpret_cast<const float4*>(p2);
        const float4 w1 = *reinterpret_cast<const float4*>(p2 + 4);
        union { short8 s; unsigned short uu[8]; } a1, a2;
        a1.uu[0] = bfr(v0.x); a1.uu[1] = bfr(v0.y); a1.uu[2] = bfr(v0.z); a1.uu[3] = bfr(v0.w);
        a1.uu[4] = bfr(v1.x); a1.uu[5] = bfr(v1.y); a1.uu[6] = bfr(v1.z); a1.uu[7] = bfr(v1.w);
        a2.uu[0] = bfr(w0.x); a2.uu[1] = bfr(w0.y); a2.uu[2] = bfr(w0.z); a2.uu[3] = bfr(w0.w);
        a2.uu[4] = bfr(w1.x); a2.uu[5] = bfr(w1.y); a2.uu[6] = bfr(w1.z); a2.uu[7] = bfr(w1.w);
        ar = a1.s; ai = a2.s;
      }
      accR[m] = __builtin_amdgcn_mfma_f32_16x16x32_bf16(ar, xb, accR[m], 0, 0, 0);
      accI[m] = __builtin_amdgcn_mfma_f32_16x16x32_bf16(ai, xb, accI[m], 0, 0, 0);
    }
  }

  // ---- epilogue: pure compute + NT store (noise already in regs) ----
  const float scale = 0.04419417382415922f;  // 1/sqrt(512)
  const float nstd  = 0.01f;
  #pragma unroll
  for (int m = 0; m < 4; ++m)
    #pragma unroll
    for (int r = 0; r < 4; ++r) {
      const size_t idx = obase + (size_t)(m * 16 + r) * NP;
      const float yr = accR[m][r] * scale + nrv[m][r] * nstd;
      const float yi = accI[m][r] * scale + niv[m][r] * nstd;
      __builtin_nontemporal_store(sqrtf(yr * yr + yi * yi), outg + idx);
    }
}

extern "C" void kernel_launch(void* const* d_in, const int* in_sizes, int n_in,
                              void* d_out, int out_size, void* d_ws, size_t ws_size,
                              hipStream_t stream) {
  const float* x  = (const float*)d_in[0];
  const float* Hr = (const float*)d_in[1];
  const float* Hi = (const float*)d_in[2];
  const float* nr = (const float*)d_in[3];
  const float* ni = (const float*)d_in[4];
  float* out = (float*)d_out;

  const size_t HN = (size_t)NBATCH * NC * NC;  // 2,097,152 elems per H array

  if (ws_size >= HN * 2 * sizeof(unsigned short)) {
    unsigned short* hrb = (unsigned short*)d_ws;
    unsigned short* hib = hrb + HN;
    hipLaunchKernelGGL(cvt_h_kernel, dim3(2048), dim3(256), 0, stream, Hr, Hi, hrb, hib);
    hipLaunchKernelGGL((rayleigh_main<1>), dim3(NBATCH * 2 * NBN), dim3(512), 0, stream,
                       x, Hr, Hi, hrb, hib, nr, ni, out);
  } else {
    hipLaunchKernelGGL((rayleigh_main<0>), dim3(NBATCH * 2 * NBN), dim3(512), 0, stream,
                       x, Hr, Hi, (const unsigned short*)nullptr, (const unsigned short*)nullptr,
                       nr, ni, out);
  }
}

// Round 6
// 107.244 us; speedup vs baseline: 1.3228x; 1.3228x over previous
//
#include <hip/hip_runtime.h>
#include <hip/hip_bf16.h>
#include <math.h>

// out[b,i,p] = sqrt(yr^2+yi^2); yr/yi = (Hr/Hi[b] @ x[b])*scale + noise*0.01
// B=32, C=256, P=3136. Memory-bound (~292-312MB HBM observed, floor ~50-65us).
// Round-6: H pre-PERMUTED in ws to the exact per-(b,bm,kt) LDS image ->
// main-kernel H DMA is fully contiguous (8 dense lines/instr vs 64 sparse:
// 8x request amplification removed). Rest identical to round-3 (131us best).

#define NBATCH 32
#define NC 256
#define NP 3136
#define BM 128
#define BN 64
#define BK 32
#define NBN 49
#define NKI 8          // 256/32 K-steps

typedef __attribute__((ext_vector_type(8))) short short8;
typedef __attribute__((ext_vector_type(4))) float f32x4;

static __device__ __forceinline__ void gload16(const void* g, void* l) {
  __builtin_amdgcn_global_load_lds(
      (const __attribute__((address_space(1))) void*)g,
      (__attribute__((address_space(3))) void*)l, 16, 0, 0);
}

static __device__ __forceinline__ unsigned short bfr(float f) {
  __hip_bfloat16 h = __float2bfloat16(f);   // RNE; pairs into v_cvt_pk_bf16_f32
  return *reinterpret_cast<unsigned short*>(&h);
}

// ---- pre-pass: permute Hr/Hi fp32 -> bf16 ws in LDS-image layout ----
// ws elem index: (((b2m*8 + kt)*2 + plane)*4096) + fq*1024 + row*8 + e
//   b2m = b*2+bm (0..63), kt = K-tile (0..7), plane 0=r 1=i,
//   fq = k-chunk (0..3), row = M-row within 128-tile, e = k within chunk.
// Per (b,bm,kt): 16KB contiguous == exactly the two 8KB LDS tiles.
__global__ __launch_bounds__(256)
void perm_h_kernel(const float* __restrict__ hr, const float* __restrict__ hi,
                   unsigned short* __restrict__ ws)
{
  const int blk   = blockIdx.x;        // b*16 + bm*8 + kt  (512 blocks)
  const int kt    = blk & 7;
  const int b2m   = blk >> 3;          // b*2 + bm
  const int plane = threadIdx.x >> 7;  // 0..1
  const int row   = threadIdx.x & 127; // 0..127
  const int b     = b2m >> 1;
  const int bm    = b2m & 1;

  const float* src = (plane ? hi : hr)
      + ((size_t)b * NC + bm * 128 + row) * NC + kt * 32;
  unsigned short* dst = ws + ((size_t)(b2m * 8 + kt) * 2 + plane) * 4096 + row * 8;

  #pragma unroll
  for (int fq = 0; fq < 4; ++fq) {
    const float4 v0 = *reinterpret_cast<const float4*>(src + fq * 8);
    const float4 v1 = *reinterpret_cast<const float4*>(src + fq * 8 + 4);
    union { uint4 v; unsigned short u[8]; } o;
    o.u[0] = bfr(v0.x); o.u[1] = bfr(v0.y); o.u[2] = bfr(v0.z); o.u[3] = bfr(v0.w);
    o.u[4] = bfr(v1.x); o.u[5] = bfr(v1.y); o.u[6] = bfr(v1.z); o.u[7] = bfr(v1.w);
    *reinterpret_cast<uint4*>(dst + fq * 1024) = o.v;
  }
}

// x LDS: fp32 [k 0..31][p 0..63], phys 16B-chunk = logical ^ swz(k>>3) (0 bank
// conflicts, verified r2/r3). H LDS: bf16 [fq][row][8] (2-way = free).
// Structure == round-3 (best, 131us): __syncthreads 1/iter, depth-2 DMA dbuf,
// NT noise loads in-loop, plain out stores. Only H source layout changed.
template<int PRE>
__global__ __launch_bounds__(512, 4)
void rayleigh_main(const float* __restrict__ xg,
                   const float* __restrict__ Hrg,
                   const float* __restrict__ Hig,
                   const unsigned short* __restrict__ Hperm,
                   const float* __restrict__ nrg,
                   const float* __restrict__ nig,
                   float* __restrict__ outg)
{
  __shared__ float x_lds[2][BK * BN];            // 2 x 8KB
  __shared__ unsigned short hr_lds[2][4096];     // 2 x 8KB  [fq][row][8]
  __shared__ unsigned short hi_lds[2][4096];     // 2 x 8KB

  // XCD-chunked bijection: 3136 = 8*392. Each XCD owns 4 whole batches ->
  // x[b] + permuted-H slab L2-resident per XCD.
  const int raw = blockIdx.x;
  const int v   = (raw & 7) * 392 + (raw >> 3);
  const int b   = v / 98;
  const int r2  = v - b * 98;
  const int bm  = r2 / 49;
  const int bn  = r2 - bm * 49;

  const int tid  = threadIdx.x;
  const int lane = tid & 63;
  const int wave = tid >> 6;      // 8 waves: 2(M) x 4(N)
  const int wm   = wave >> 2;
  const int wn   = wave & 3;
  const int fr   = lane & 15;
  const int fq   = lane >> 4;

  const float* xsrc = xg + (size_t)b * NC * NP + (size_t)bn * BN;
  const size_t hrowbase = (size_t)b * NC + bm * BM;
  const size_t hpbase = (size_t)((b * 2 + bm) * 8);   // + kt, then *2*4096

  // stage one K-tile: x 8KB (wave w -> chunk w) + H 16KB (wave w -> 2 chunks,
  // both fully CONTIGUOUS 1KB from the permuted ws). 3 vmem ops/wave.
  auto stage = [&](int t, int buf) {
    {
      const int C16 = wave * 64 + lane;          // 16B chunk idx in 8KB x-tile
      const int k   = C16 >> 4;
      const int cp  = C16 & 15;
      const int fqk = k >> 3;
      const int cl  = cp ^ (((fqk & 1) << 2) | (fqk >> 1));
      const float* src = xsrc + (size_t)(t * BK + k) * NP + cl * 4;
      gload16(src, (char*)x_lds[buf] + wave * 1024);
    }
    if constexpr (PRE) {
      #pragma unroll
      for (int i = 0; i < 2; ++i) {
        const int c     = wave * 2 + i;          // 0..15
        const int plane = c >> 3;                // 0=r, 1=i
        const int fqc   = (c >> 1) & 3;
        const int half  = c & 1;
        unsigned short* hl = plane ? hi_lds[buf] : hr_lds[buf];
        const unsigned short* src = Hperm
            + ((hpbase + t) * 2 + plane) * 4096
            + fqc * 1024 + (half * 64 + lane) * 8;   // contiguous per lane
        gload16(src, (char*)hl + fqc * 2048 + half * 1024);
      }
    }
  };

  f32x4 accR[4], accI[4];
  #pragma unroll
  for (int m = 0; m < 4; ++m) {
    accR[m] = (f32x4){0.f, 0.f, 0.f, 0.f};
    accI[m] = (f32x4){0.f, 0.f, 0.f, 0.f};
  }
  float nrv[4][4], niv[4][4];

  const size_t obase = ((size_t)b * NC + bm * BM + wm * 64 + fq * 4) * NP
                     + (size_t)bn * BN + wn * 16 + fr;
  const int xork = ((fq & 1) << 6) | ((fq >> 1) << 4);
  const int pcol = ((wn * 16 + fr) << 2) ^ xork;

  stage(0, 0);

  #pragma unroll
  for (int t = 0; t < NKI; ++t) {
    __syncthreads();                       // buffers[t&1] ready (drains DMA)
    if (t + 1 < NKI) stage(t + 1, (t + 1) & 1);

    // noise prefetch chunk t: 4 NT dword loads -> regs (overlaps GEMM phase)
    {
      const int m = t >> 1, rb = (t & 1) * 2;
      #pragma unroll
      for (int r = 0; r < 2; ++r) {
        const size_t idx = obase + (size_t)(m * 16 + rb + r) * NP;
        nrv[m][rb + r] = __builtin_nontemporal_load(nrg + idx);
        niv[m][rb + r] = __builtin_nontemporal_load(nig + idx);
      }
    }

    // B-fragment: 8 swizzled ds_read_b32 + pk-convert (0 bank conflicts)
    const char* xbuf = (const char*)x_lds[t & 1];
    union { short8 s; unsigned short u[8]; } u;
    #pragma unroll
    for (int j = 0; j < 8; ++j) {
      const float f = *reinterpret_cast<const float*>(xbuf + ((fq * 8 + j) << 8) + pcol);
      u.u[j] = bfr(f);
    }
    const short8 xb = u.s;

    // A-fragments from LDS (ds_read_b128, 2-way = free) + MFMA
    #pragma unroll
    for (int m = 0; m < 4; ++m) {
      const int row = wm * 64 + m * 16 + fr;
      short8 ar, ai;
      if constexpr (PRE) {
        ar = *reinterpret_cast<const short8*>(&hr_lds[t & 1][fq * 1024 + row * 8]);
        ai = *reinterpret_cast<const short8*>(&hi_lds[t & 1][fq * 1024 + row * 8]);
      } else {
        const float* p1 = Hrg + (hrowbase + row) * NC + t * BK + fq * 8;
        const float* p2 = Hig + (hrowbase + row) * NC + t * BK + fq * 8;
        const float4 v0 = *reinterpret_cast<const float4*>(p1);
        const float4 v1 = *reinterpret_cast<const float4*>(p1 + 4);
        const float4 w0 = *reinterpret_cast<const float4*>(p2);
        const float4 w1 = *reinterpret_cast<const float4*>(p2 + 4);
        union { short8 s; unsigned short uu[8]; } a1, a2;
        a1.uu[0] = bfr(v0.x); a1.uu[1] = bfr(v0.y); a1.uu[2] = bfr(v0.z); a1.uu[3] = bfr(v0.w);
        a1.uu[4] = bfr(v1.x); a1.uu[5] = bfr(v1.y); a1.uu[6] = bfr(v1.z); a1.uu[7] = bfr(v1.w);
        a2.uu[0] = bfr(w0.x); a2.uu[1] = bfr(w0.y); a2.uu[2] = bfr(w0.z); a2.uu[3] = bfr(w0.w);
        a2.uu[4] = bfr(w1.x); a2.uu[5] = bfr(w1.y); a2.uu[6] = bfr(w1.z); a2.uu[7] = bfr(w1.w);
        ar = a1.s; ai = a2.s;
      }
      accR[m] = __builtin_amdgcn_mfma_f32_16x16x32_bf16(ar, xb, accR[m], 0, 0, 0);
      accI[m] = __builtin_amdgcn_mfma_f32_16x16x32_bf16(ai, xb, accI[m], 0, 0, 0);
    }
  }

  // ---- epilogue: pure compute + store (noise already in regs) ----
  const float scale = 0.04419417382415922f;  // 1/sqrt(512)
  const float nstd  = 0.01f;
  #pragma unroll
  for (int m = 0; m < 4; ++m)
    #pragma unroll
    for (int r = 0; r < 4; ++r) {
      const size_t idx = obase + (size_t)(m * 16 + r) * NP;
      const float yr = accR[m][r] * scale + nrv[m][r] * nstd;
      const float yi = accI[m][r] * scale + niv[m][r] * nstd;
      outg[idx] = sqrtf(yr * yr + yi * yi);
    }
}

extern "C" void kernel_launch(void* const* d_in, const int* in_sizes, int n_in,
                              void* d_out, int out_size, void* d_ws, size_t ws_size,
                              hipStream_t stream) {
  const float* x  = (const float*)d_in[0];
  const float* Hr = (const float*)d_in[1];
  const float* Hi = (const float*)d_in[2];
  const float* nr = (const float*)d_in[3];
  const float* ni = (const float*)d_in[4];
  float* out = (float*)d_out;

  const size_t HN = (size_t)NBATCH * NC * NC;  // 2,097,152 elems per H array

  if (ws_size >= HN * 2 * sizeof(unsigned short)) {
    unsigned short* hperm = (unsigned short*)d_ws;
    hipLaunchKernelGGL(perm_h_kernel, dim3(512), dim3(256), 0, stream, Hr, Hi, hperm);
    hipLaunchKernelGGL((rayleigh_main<1>), dim3(NBATCH * 2 * NBN), dim3(512), 0, stream,
                       x, Hr, Hi, hperm, nr, ni, out);
  } else {
    hipLaunchKernelGGL((rayleigh_main<0>), dim3(NBATCH * 2 * NBN), dim3(512), 0, stream,
                       x, Hr, Hi, (const unsigned short*)nullptr, nr, ni, out);
  }
}